// Round 1
// baseline (17.711 us; speedup 1.0000x reference)
//
#include <hip/hip_runtime.h>
#include <math.h>

#define NQ 12
#define NN 4096
#define BLK 1024

__global__ __launch_bounds__(BLK) void qubit_layer_kernel(
    const float* __restrict__ x,       // (B, 2, N)
    const float* __restrict__ alphas,  // (12,)
    const float* __restrict__ betas,
    const float* __restrict__ thetas,
    const float* __restrict__ phis,
    float* __restrict__ out)           // (B, 2, N)
{
    __shared__ float sre[NN];
    __shared__ float sim[NN];
    __shared__ float ang[4][NQ];

    const int b = blockIdx.x;
    const int t = threadIdx.x;

    if (t < NQ) {
        ang[0][t] = alphas[t];
        ang[1][t] = betas[t];
        ang[2][t] = thetas[t];
        ang[3][t] = phis[t];
    }

    const float* xr = x + (size_t)b * 2 * NN;
    const float* xi = xr + NN;

    __syncthreads();

    // ---- load + input phase: v = x * exp(i * (bit ? beta : alpha)) ----
    #pragma unroll
    for (int j = t; j < NN; j += BLK) {
        float re = xr[j], im = xi[j];
        float a = 0.f;
        #pragma unroll
        for (int q = 0; q < NQ; ++q) {
            int bit = (j >> (NQ - 1 - q)) & 1;
            a += bit ? ang[1][q] : ang[0][q];
        }
        float s, c;
        __sincosf(a, &s, &c);
        sre[j] = re * c - im * s;
        sim[j] = re * s + im * c;
    }
    __syncthreads();

    // ---- 12 butterfly stages: v = v @ (BS kron^12), per-bit 2x2 ----
    const float rs = 0.70710678118654752f;
    for (int p = 0; p < NQ; ++p) {
        #pragma unroll
        for (int q = t; q < NN / 2; q += BLK) {
            int j0 = ((q >> p) << (p + 1)) | (q & ((1 << p) - 1));
            int j1 = j0 | (1 << p);
            float ur = sre[j0], ui = sim[j0];
            float wr = sre[j1], wi = sim[j1];
            // new_u = (u + i*w)/sqrt2 ; new_w = (i*u + w)/sqrt2
            sre[j0] = (ur - wi) * rs;
            sim[j0] = (ui + wr) * rs;
            sre[j1] = (wr - ui) * rs;
            sim[j1] = (wi + ur) * rs;
        }
        __syncthreads();
    }

    // ---- theta phase (bit==0 contributes theta, bit==1 contributes 0) ----
    #pragma unroll
    for (int j = t; j < NN; j += BLK) {
        float a = 0.f;
        #pragma unroll
        for (int q = 0; q < NQ; ++q) {
            int bit = (j >> (NQ - 1 - q)) & 1;
            a += bit ? 0.f : ang[2][q];
        }
        float s, c;
        __sincosf(a, &s, &c);
        float re = sre[j], im = sim[j];
        sre[j] = re * c - im * s;
        sim[j] = re * s + im * c;
    }
    __syncthreads();

    // ---- second 12 butterfly stages ----
    for (int p = 0; p < NQ; ++p) {
        #pragma unroll
        for (int q = t; q < NN / 2; q += BLK) {
            int j0 = ((q >> p) << (p + 1)) | (q & ((1 << p) - 1));
            int j1 = j0 | (1 << p);
            float ur = sre[j0], ui = sim[j0];
            float wr = sre[j1], wi = sim[j1];
            sre[j0] = (ur - wi) * rs;
            sim[j0] = (ui + wr) * rs;
            sre[j1] = (wr - ui) * rs;
            sim[j1] = (wi + ur) * rs;
        }
        __syncthreads();
    }

    // ---- phi phase + store ----
    float* outr = out + (size_t)b * 2 * NN;
    float* outi = outr + NN;
    #pragma unroll
    for (int j = t; j < NN; j += BLK) {
        float a = 0.f;
        #pragma unroll
        for (int q = 0; q < NQ; ++q) {
            int bit = (j >> (NQ - 1 - q)) & 1;
            a += bit ? 0.f : ang[3][q];
        }
        float s, c;
        __sincosf(a, &s, &c);
        float re = sre[j], im = sim[j];
        outr[j] = re * c - im * s;
        outi[j] = re * s + im * c;
    }
}

extern "C" void kernel_launch(void* const* d_in, const int* in_sizes, int n_in,
                              void* d_out, int out_size, void* d_ws, size_t ws_size,
                              hipStream_t stream) {
    const float* x      = (const float*)d_in[0];
    const float* alphas = (const float*)d_in[1];
    const float* betas  = (const float*)d_in[2];
    const float* thetas = (const float*)d_in[3];
    const float* phis   = (const float*)d_in[4];
    float* out = (float*)d_out;

    const int batch = 64;
    qubit_layer_kernel<<<batch, BLK, 0, stream>>>(x, alphas, betas, thetas, phis, out);
}

// Round 2
// 10.690 us; speedup vs baseline: 1.6569x; 1.6569x over previous
//
#include <hip/hip_runtime.h>
#include <math.h>

#define NN 4096
#define BLK 512
#define EPT 8
#define EXSZ (NN + (NN >> 5))   // padded: idx(j) = j + (j>>5)

__device__ __forceinline__ void cmul(float& ar, float& ai, float br, float bi) {
    float nr = ar * br - ai * bi;
    float ni = ar * bi + ai * br;
    ar = nr; ai = ni;
}

__device__ __forceinline__ void bfly_pair(float* vr, float* vi, int a, int b) {
    // new_u = u + i*w ; new_w = w + i*u   (1/sqrt2 folded into phase tables)
    float ur = vr[a], ui = vi[a], wr = vr[b], wi = vi[b];
    vr[a] = ur - wi; vi[a] = ui + wr;
    vr[b] = wr - ui; vi[b] = wi + ur;
}

__device__ __forceinline__ void bfly3(float* vr, float* vi) {
    bfly_pair(vr, vi, 0, 1); bfly_pair(vr, vi, 2, 3); bfly_pair(vr, vi, 4, 5); bfly_pair(vr, vi, 6, 7);
    bfly_pair(vr, vi, 0, 2); bfly_pair(vr, vi, 1, 3); bfly_pair(vr, vi, 4, 6); bfly_pair(vr, vi, 5, 7);
    bfly_pair(vr, vi, 0, 4); bfly_pair(vr, vi, 1, 5); bfly_pair(vr, vi, 2, 6); bfly_pair(vr, vi, 3, 7);
}

// Exchange register blocking: current layout has bits [PC..PC+2] in registers,
// next layout has bits [PN..PN+2] in registers. j = ((t>>P)<<(P+3)) | (r<<P) | (t & ((1<<P)-1))
template<int PC, int PN>
__device__ __forceinline__ void exchange(float2* ex, float* vr, float* vi, int t) {
    const int basec = ((t >> PC) << (PC + 3)) | (t & ((1 << PC) - 1));
    #pragma unroll
    for (int r = 0; r < EPT; ++r) {
        int j = basec + (r << PC);
        ex[j + (j >> 5)] = make_float2(vr[r], vi[r]);
    }
    __syncthreads();
    const int basen = ((t >> PN) << (PN + 3)) | (t & ((1 << PN) - 1));
    #pragma unroll
    for (int r = 0; r < EPT; ++r) {
        int j = basen + (r << PN);
        float2 v = ex[j + (j >> 5)];
        vr[r] = v.x; vi[r] = v.y;
    }
}

__global__ __launch_bounds__(BLK) void qubit_layer_kernel(
    const float* __restrict__ x,       // (B, 2, N)
    const float* __restrict__ alphas,
    const float* __restrict__ betas,
    const float* __restrict__ thetas,
    const float* __restrict__ phis,
    float* __restrict__ out)           // (B, 2, N)
{
    __shared__ float2 ex0[EXSZ];
    __shared__ float2 ex1[EXSZ];
    __shared__ float2 tbl[6][64];      // [set*2+half][idx]; set 0=in,1=theta,2=phi; half 0=low,1=high

    const int b = blockIdx.x;
    const int t = threadIdx.x;

    // ---- build phase tables: angle(j) = low(l) + high(h), l=j&63 (qubits 6..11), h=j>>6 (qubits 0..5)
    if (t < 384) {
        int part = t >> 6;   // 0..5
        int idx  = t & 63;
        int set  = part >> 1;
        int half = part & 1;
        float a = 0.f;
        #pragma unroll
        for (int m = 0; m < 6; ++m) {
            int q = half ? m : (6 + m);
            int bit = (idx >> (5 - m)) & 1;
            float av, bv;
            if (set == 0)      { av = alphas[q]; bv = betas[q]; }
            else if (set == 1) { av = thetas[q]; bv = 0.f; }
            else               { av = phis[q];   bv = 0.f; }
            a += bit ? bv : av;
        }
        float s, c;
        __sincosf(a, &s, &c);
        // fold each BS's (1/sqrt2)^12 = 1/64 into theta-low and phi-low tables
        float sc = (set >= 1 && half == 0) ? (1.0f / 64.0f) : 1.0f;
        tbl[part][idx] = make_float2(c * sc, s * sc);
    }

    float vr[EPT], vi[EPT];

    // ---- load, MP1 layout (p=0): j = t*8 + r, vectorized
    const float* xr = x + (size_t)b * 2 * NN;
    const float* xi = xr + NN;
    {
        float4 a0 = ((const float4*)(xr + t * EPT))[0];
        float4 a1 = ((const float4*)(xr + t * EPT))[1];
        float4 c0 = ((const float4*)(xi + t * EPT))[0];
        float4 c1 = ((const float4*)(xi + t * EPT))[1];
        vr[0] = a0.x; vr[1] = a0.y; vr[2] = a0.z; vr[3] = a0.w;
        vr[4] = a1.x; vr[5] = a1.y; vr[6] = a1.z; vr[7] = a1.w;
        vi[0] = c0.x; vi[1] = c0.y; vi[2] = c0.z; vi[3] = c0.w;
        vi[4] = c1.x; vi[5] = c1.y; vi[6] = c1.z; vi[7] = c1.w;
    }
    __syncthreads();   // tables ready

    // ---- D_in: h = t>>3 (const per thread), l = (t&7)*8 + r
    {
        float2 eh = tbl[1][t >> 3];
        #pragma unroll
        for (int r = 0; r < EPT; ++r) {
            float2 el = tbl[0][((t & 7) << 3) + r];
            float er = el.x, ei = el.y;
            cmul(er, ei, eh.x, eh.y);
            cmul(vr[r], vi[r], er, ei);
        }
    }

    // ---- BS1: 4 macro-passes of 3 register stages
    bfly3(vr, vi);
    exchange<0, 3>(ex0, vr, vi, t); bfly3(vr, vi);
    exchange<3, 6>(ex1, vr, vi, t); bfly3(vr, vi);
    exchange<6, 9>(ex0, vr, vi, t); bfly3(vr, vi);

    // ---- D_theta at p=9 layout: j = t + (r<<9); l = t&63, h = (t>>6) + (r<<3)
    {
        float2 el = tbl[2][t & 63];
        #pragma unroll
        for (int r = 0; r < EPT; ++r) {
            float2 eh = tbl[3][(t >> 6) + (r << 3)];
            float er = el.x, ei = el.y;
            cmul(er, ei, eh.x, eh.y);
            cmul(vr[r], vi[r], er, ei);
        }
    }

    // ---- BS2
    exchange<9, 0>(ex1, vr, vi, t); bfly3(vr, vi);
    exchange<0, 3>(ex0, vr, vi, t); bfly3(vr, vi);
    exchange<3, 6>(ex1, vr, vi, t); bfly3(vr, vi);
    exchange<6, 9>(ex0, vr, vi, t); bfly3(vr, vi);

    // ---- D_phi + store at p=9 layout: j = t + (r<<9), coalesced b32 stores
    float* outr = out + (size_t)b * 2 * NN;
    float* outi = outr + NN;
    {
        float2 el = tbl[4][t & 63];
        #pragma unroll
        for (int r = 0; r < EPT; ++r) {
            float2 eh = tbl[5][(t >> 6) + (r << 3)];
            float er = el.x, ei = el.y;
            cmul(er, ei, eh.x, eh.y);
            cmul(vr[r], vi[r], er, ei);
            outr[t + (r << 9)] = vr[r];
            outi[t + (r << 9)] = vi[r];
        }
    }
}

extern "C" void kernel_launch(void* const* d_in, const int* in_sizes, int n_in,
                              void* d_out, int out_size, void* d_ws, size_t ws_size,
                              hipStream_t stream) {
    const float* x      = (const float*)d_in[0];
    const float* alphas = (const float*)d_in[1];
    const float* betas  = (const float*)d_in[2];
    const float* thetas = (const float*)d_in[3];
    const float* phis   = (const float*)d_in[4];
    float* out = (float*)d_out;

    const int batch = in_sizes[0] / (2 * NN);   // 64
    qubit_layer_kernel<<<batch, BLK, 0, stream>>>(x, alphas, betas, thetas, phis, out);
}